// Round 10
// baseline (60.122 us; speedup 1.0000x reference)
//
#include <hip/hip_runtime.h>
#include <hip/hip_bf16.h>
#include <math.h>

#define CIN   128
#define DDIM  64
#define KCB   512
#define HWSZ  4096
#define NPIX  131072
#define NOUTQ 8388608
#define XPAD  136   // shorts per pixel row in a wave's x/z slot

typedef short bf16x8 __attribute__((ext_vector_type(8)));
typedef float f32x4  __attribute__((ext_vector_type(4)));
typedef unsigned int u32x2 __attribute__((ext_vector_type(2)));

// d_ws layout (bytes). Requires ws_size >= 100352 (~98 KB).
#define WS_CBA  0        // bf16 -2c A-frags: 65536 B
#define WS_WA   65536    // bf16 W A-frags:   16384 B
#define WS_CBN  81920    // f32 ||c||^2:       2048 B
#define WS_PART 83968    // f32 partials[4096]: 16384 B

__device__ __forceinline__ unsigned int bcu(float f){ union{float f;unsigned int u;}v; v.f=f; return v.u; }
__device__ __forceinline__ float bcf(unsigned int u){ union{unsigned int u;float f;}v; v.u=u; return v.f; }
__device__ __forceinline__ unsigned int pkbf(float a, float b){   // 2xf32 -> packed bf16 (RNE)
    union { __hip_bfloat162 h; unsigned int u; } v;
    v.h = __float22bfloat162_rn(make_float2(a, b));
    return v.u;
}

#define MFMA16(A, B, C) __builtin_amdgcn_mfma_f32_16x16x32_bf16((A), (B), (C), 0, 0, 0)

// ---------------------------------------------------------------------------
// k0: build global frag arrays in d_ws (verified R8/R9). grid 32 x 256.
// ---------------------------------------------------------------------------
__global__ __launch_bounds__(256) void vq_prep(
    const float* __restrict__ cb, const float* __restrict__ w,
    unsigned short* __restrict__ cbA, unsigned short* __restrict__ wA,
    float* __restrict__ cbn)
{
    const int gid = blockIdx.x * 256 + threadIdx.x;   // [0, 8192)
    {   // cbA: A[k][d] = -2*cb
        int k = gid >> 4, dg = gid & 15;
        f32x4 v = *(const f32x4*)(cb + (size_t)k * DDIM + dg * 4);
        u32x2 pv = { pkbf(-2.f * v[0], -2.f * v[1]), pkbf(-2.f * v[2], -2.f * v[3]) };
        int ct = k >> 4, ks = dg >> 3, lhi = (dg >> 1) & 3, ll = (k & 15) | (lhi << 4);
        *(u32x2*)(cbA + ((ct * 2 + ks) * 64 + ll) * 8 + (dg & 1) * 4) = pv;
    }
    if (gid < 2048) {   // wA: A[d][c]
        int d = gid >> 5, cg = gid & 31;
        f32x4 v = *(const f32x4*)(w + (size_t)d * CIN + cg * 4);
        u32x2 pv = { pkbf(v[0], v[1]), pkbf(v[2], v[3]) };
        int dt = d >> 4, ks = cg >> 3, lhi = (cg >> 1) & 3, ll = (d & 15) | (lhi << 4);
        *(u32x2*)(wA + ((dt * 4 + ks) * 64 + ll) * 8 + (cg & 1) * 4) = pv;
    }
    if (gid < KCB) {    // ||c_k||^2 exact f32
        const f32x4* row = (const f32x4*)(cb + (size_t)gid * DDIM);
        float s = 0.f;
        #pragma unroll
        for (int j = 0; j < DDIM / 4; ++j) {
            f32x4 v = row[j];
            s = fmaf(v[0], v[0], s); s = fmaf(v[1], v[1], s);
            s = fmaf(v[2], v[2], s); s = fmaf(v[3], v[3], s);
        }
        cbn[gid] = s;
    }
}

// stage x (regs->bf16->own slot), 16-MFMA projection (W frags L1/L2-hot),
// z roundtrip through the slot -> zb frags. Verified R7/R8/R9 semantics.
__device__ __forceinline__ void proj_tile(
    const float (&xr)[32], unsigned short* xrow,
    const unsigned short* __restrict__ wA, const float* __restrict__ bias,
    int lg, int klg, int l,
    f32x4& zA, f32x4& zB, f32x4& zC, f32x4& zD, bf16x8& zb0, bf16x8& zb1)
{
    #pragma unroll
    for (int j = 0; j < 8; ++j) {
        u32x2 pv = { pkbf(xr[4*j+0], xr[4*j+1]), pkbf(xr[4*j+2], xr[4*j+3]) };
        *(u32x2*)(xrow + lg * 32 + 4 * j) = pv;   // ds_write_b64
    }
    zA = *(const f32x4*)(bias +  0 + klg);
    zB = *(const f32x4*)(bias + 16 + klg);
    zC = *(const f32x4*)(bias + 32 + klg);
    zD = *(const f32x4*)(bias + 48 + klg);
    #pragma unroll
    for (int ks = 0; ks < 4; ++ks) {
        bf16x8 xf = *(const bf16x8*)(xrow + ks * 32 + lg * 8);
        bf16x8 w0 = *(const bf16x8*)(wA + ((0 * 4 + ks) * 64 + l) * 8);
        bf16x8 w1 = *(const bf16x8*)(wA + ((1 * 4 + ks) * 64 + l) * 8);
        bf16x8 w2 = *(const bf16x8*)(wA + ((2 * 4 + ks) * 64 + l) * 8);
        bf16x8 w3 = *(const bf16x8*)(wA + ((3 * 4 + ks) * 64 + l) * 8);
        zA = MFMA16(w0, xf, zA);
        zB = MFMA16(w1, xf, zB);
        zC = MFMA16(w2, xf, zC);
        zD = MFMA16(w3, xf, zD);
    }
    // z -> bf16 -> same slot row (same-wave LDS ordering via lgkmcnt)
    unsigned int* zr = (unsigned int*)xrow;
    u32x2 z0 = { pkbf(zA[0], zA[1]), pkbf(zA[2], zA[3]) };
    u32x2 z1 = { pkbf(zB[0], zB[1]), pkbf(zB[2], zB[3]) };
    u32x2 z2 = { pkbf(zC[0], zC[1]), pkbf(zC[2], zC[3]) };
    u32x2 z3 = { pkbf(zD[0], zD[1]), pkbf(zD[2], zD[3]) };
    *(u32x2*)(zr +  0 + lg * 2) = z0;
    *(u32x2*)(zr +  8 + lg * 2) = z1;
    *(u32x2*)(zr + 16 + lg * 2) = z2;
    *(u32x2*)(zr + 24 + lg * 2) = z3;
    zb0 = *(const bf16x8*)(xrow + lg * 8);        // d = lg*8 + e
    zb1 = *(const bf16x8*)(xrow + 32 + lg * 8);   // d = 32 + lg*8 + e
}

// ---------------------------------------------------------------------------
// k1: per-wave pipeline, TWO adjacent 16-px tiles per wave -> one codebook
// scan serves both (L2 frag traffic halved vs R9). 1024 blocks x 256 thr =
// 4096 waves (16/CU), no barriers, no atomics. Fused gather/store/loss.
// ---------------------------------------------------------------------------
__global__ __launch_bounds__(256, 4) void vq_scan_out(
    const float* __restrict__ x,      // [32][128][4096]
    const float* __restrict__ bias,   // [64]
    const unsigned short* __restrict__ cbA,
    const unsigned short* __restrict__ wA,
    const float* __restrict__ cbn,
    const float* __restrict__ cb,
    float* __restrict__ out,          // [32][64][4096]
    float* __restrict__ part)         // [4096]
{
    __shared__ __align__(16) unsigned short sX[4 * 16 * XPAD];   // 17.4 KB

    const int t   = threadIdx.x;
    const int l   = t & 63;
    const int wv  = t >> 6;
    const int p16 = l & 15;
    const int lg  = l >> 4;
    const int klg = lg * 4;

    const int wid  = blockIdx.x * 4 + wv;
    const int pixg = wid * 32;               // 32 adjacent pixels per wave
    const int b    = pixg >> 12;
    const int hw0  = pixg & 4095;
    const float* xp = x + ((size_t)b * CIN + (size_t)lg * 32) * HWSZ + hw0 + p16;
    unsigned short* xrow = sX + wv * (16 * XPAD) + p16 * XPAD;

    // ---- paired x loads: full 128B line per c-plane (R7-verified) ----
    float xr0[32], xr1[32];
    #pragma unroll
    for (int j = 0; j < 32; ++j) {
        xr0[j] = xp[(size_t)j * HWSZ];
        xr1[j] = xp[(size_t)j * HWSZ + 16];
    }

    f32x4 zaA0, zaA1, zaA2, zaA3, zaB0, zaB1, zaB2, zaB3;
    bf16x8 zb00, zb01, zb10, zb11;
    proj_tile(xr0, xrow, wA, bias, lg, klg, l, zaA0, zaA1, zaA2, zaA3, zb00, zb01);
    proj_tile(xr1, xrow, wA, bias, lg, klg, l, zaB0, zaB1, zaB2, zaB3, zb10, zb11);

    // ---- one codebook scan, both tiles; packed-key argmin (R7-verified) ----
    float rm00 = INFINITY, rm01 = INFINITY, rm10 = INFINITY, rm11 = INFINITY;
    #pragma unroll 4
    for (int ct = 0; ct < 32; ++ct) {
        f32x4 cinit = *(const f32x4*)(cbn + ct * 16 + klg);   // init = ||c||^2 (L1-hot)
        bf16x8 c0 = *(const bf16x8*)(cbA + ((ct * 2 + 0) * 64 + l) * 8);
        bf16x8 c1 = *(const bf16x8*)(cbA + ((ct * 2 + 1) * 64 + l) * 8);
        f32x4 a0 = MFMA16(c0, zb00, cinit); a0 = MFMA16(c1, zb01, a0);
        f32x4 a1 = MFMA16(c0, zb10, cinit); a1 = MFMA16(c1, zb11, a1);
        unsigned int kbse = (unsigned int)(ct * 16 + klg);
        rm00 = fminf(rm00, bcf((bcu(a0[0]) & 0xFFFFFE00u) | (kbse + 0)));
        rm01 = fminf(rm01, bcf((bcu(a0[1]) & 0xFFFFFE00u) | (kbse + 1)));
        rm00 = fminf(rm00, bcf((bcu(a0[2]) & 0xFFFFFE00u) | (kbse + 2)));
        rm01 = fminf(rm01, bcf((bcu(a0[3]) & 0xFFFFFE00u) | (kbse + 3)));
        rm10 = fminf(rm10, bcf((bcu(a1[0]) & 0xFFFFFE00u) | (kbse + 0)));
        rm11 = fminf(rm11, bcf((bcu(a1[1]) & 0xFFFFFE00u) | (kbse + 1)));
        rm10 = fminf(rm10, bcf((bcu(a1[2]) & 0xFFFFFE00u) | (kbse + 2)));
        rm11 = fminf(rm11, bcf((bcu(a1[3]) & 0xFFFFFE00u) | (kbse + 3)));
    }
    float rn0 = fminf(rm00, rm01);
    rn0 = fminf(rn0, __shfl_xor(rn0, 16, 64));
    rn0 = fminf(rn0, __shfl_xor(rn0, 32, 64));
    const int kbest0 = (int)(bcu(rn0) & 511u);
    float rn1 = fminf(rm10, rm11);
    rn1 = fminf(rn1, __shfl_xor(rn1, 16, 64));
    rn1 = fminf(rn1, __shfl_xor(rn1, 32, 64));
    const int kbest1 = (int)(bcu(rn1) & 511u);

    // ---- gather winners (exact f32), store tile-sequential (R9 pattern) ----
    const float* q0r = cb + (size_t)kbest0 * DDIM;   // L2-hot
    const float* q1r = cb + (size_t)kbest1 * DDIM;
    f32x4 qa0 = *(const f32x4*)(q0r +  0 + klg);
    f32x4 qa1 = *(const f32x4*)(q0r + 16 + klg);
    f32x4 qa2 = *(const f32x4*)(q0r + 32 + klg);
    f32x4 qa3 = *(const f32x4*)(q0r + 48 + klg);
    f32x4 qb0 = *(const f32x4*)(q1r +  0 + klg);
    f32x4 qb1 = *(const f32x4*)(q1r + 16 + klg);
    f32x4 qb2 = *(const f32x4*)(q1r + 32 + klg);
    f32x4 qb3 = *(const f32x4*)(q1r + 48 + klg);
    float lsum = 0.f;
    size_t ob = ((size_t)b * DDIM + klg) * (size_t)HWSZ + hw0 + p16;
    #pragma unroll
    for (int r = 0; r < 4; ++r) {
        float e;
        e = qa0[r] - zaA0[r]; lsum = fmaf(e, e, lsum);
        e = qa1[r] - zaA1[r]; lsum = fmaf(e, e, lsum);
        e = qa2[r] - zaA2[r]; lsum = fmaf(e, e, lsum);
        e = qa3[r] - zaA3[r]; lsum = fmaf(e, e, lsum);
        out[ob + (size_t)(r +  0) * HWSZ] = qa0[r];
        out[ob + (size_t)(r + 16) * HWSZ] = qa1[r];
        out[ob + (size_t)(r + 32) * HWSZ] = qa2[r];
        out[ob + (size_t)(r + 48) * HWSZ] = qa3[r];
    }
    #pragma unroll
    for (int r = 0; r < 4; ++r) {
        float e;
        e = qb0[r] - zaB0[r]; lsum = fmaf(e, e, lsum);
        e = qb1[r] - zaB1[r]; lsum = fmaf(e, e, lsum);
        e = qb2[r] - zaB2[r]; lsum = fmaf(e, e, lsum);
        e = qb3[r] - zaB3[r]; lsum = fmaf(e, e, lsum);
        out[ob + (size_t)(r +  0) * HWSZ + 16] = qb0[r];
        out[ob + (size_t)(r + 16) * HWSZ + 16] = qb1[r];
        out[ob + (size_t)(r + 32) * HWSZ + 16] = qb2[r];
        out[ob + (size_t)(r + 48) * HWSZ + 16] = qb3[r];
    }

    // ---- one partial per wave (no atomics) ----
    #pragma unroll
    for (int off = 32; off > 0; off >>= 1)
        lsum += __shfl_down(lsum, off, 64);
    if (l == 0) part[wid] = lsum;
}

// ---------------------------------------------------------------------------
// k2: final loss reduce, 1 block x 256 thr (single writer, deterministic).
// ---------------------------------------------------------------------------
__global__ __launch_bounds__(256) void vq_loss(
    const float* __restrict__ part, float* __restrict__ loss_slot)
{
    __shared__ float sW[4];
    const int t = threadIdx.x;
    const f32x4* p4 = (const f32x4*)part;          // 1024 f32x4
    float s = 0.f;
    #pragma unroll
    for (int j = 0; j < 4; ++j) {
        f32x4 v = p4[t + j * 256];
        s += v[0] + v[1] + v[2] + v[3];
    }
    #pragma unroll
    for (int off = 32; off > 0; off >>= 1) s += __shfl_down(s, off, 64);
    if ((t & 63) == 0) sW[t >> 6] = s;
    __syncthreads();
    if (t == 0)
        *loss_slot = (sW[0] + sW[1] + sW[2] + sW[3]) * (1.25f / (float)NOUTQ);
}

extern "C" void kernel_launch(void* const* d_in, const int* in_sizes, int n_in,
                              void* d_out, int out_size, void* d_ws, size_t ws_size,
                              hipStream_t stream) {
    const float* x    = (const float*)d_in[0];   // [32,128,64,64]
    const float* w    = (const float*)d_in[1];   // [64,128]
    const float* bias = (const float*)d_in[2];   // [64]
    const float* cb   = (const float*)d_in[3];   // [512,64]
    float* out = (float*)d_out;                  // 8388608 quantized + 1 loss
    float* loss_slot = out + NOUTQ;

    char* ws = (char*)d_ws;                      // needs >= 100352 B
    unsigned short* cbA = (unsigned short*)(ws + WS_CBA);
    unsigned short* wA  = (unsigned short*)(ws + WS_WA);
    float*          cbn = (float*)(ws + WS_CBN);
    float*          prt = (float*)(ws + WS_PART);

    vq_prep    <<<32,   256, 0, stream>>>(cb, w, cbA, wA, cbn);
    vq_scan_out<<<1024, 256, 0, stream>>>(x, bias, cbA, wA, cbn, cb, out, prt);
    vq_loss    <<<1,    256, 0, stream>>>(prt, loss_slot);
}

// Round 11
// 40.453 us; speedup vs baseline: 1.4862x; 1.4862x over previous
//
#include <hip/hip_runtime.h>
#include <hip/hip_bf16.h>
#include <math.h>

#define CIN   128
#define DDIM  64
#define KCB   512
#define HWSZ  4096
#define NPIX  131072
#define NOUTQ 8388608
#define XPAD  136   // shorts per pixel row in a wave's x/z slot

typedef short bf16x8 __attribute__((ext_vector_type(8)));
typedef float f32x4  __attribute__((ext_vector_type(4)));
typedef unsigned int u32x2 __attribute__((ext_vector_type(2)));

__device__ __forceinline__ unsigned int bcu(float f){ union{float f;unsigned int u;}v; v.f=f; return v.u; }
__device__ __forceinline__ float bcf(unsigned int u){ union{unsigned int u;float f;}v; v.u=u; return v.f; }
__device__ __forceinline__ unsigned int pkbf(float a, float b){   // 2xf32 -> packed bf16 (RNE)
    union { __hip_bfloat162 h; unsigned int u; } v;
    v.h = __float22bfloat162_rn(make_float2(a, b));
    return v.u;
}

#define MFMA16(A, B, C) __builtin_amdgcn_mfma_f32_16x16x32_bf16((A), (B), (C), 0, 0, 0)

// stage x (regs->bf16->own slot), 16-MFMA projection, z roundtrip -> zb frags.
// Byte-identical semantics to the passing R7 kernel.
__device__ __forceinline__ void proj_tile(
    const float (&xr)[32], unsigned short* xrow,
    const unsigned short* sWA, const float* sBias,
    int lg, int klg, int l,
    f32x4& zA, f32x4& zB, f32x4& zC, f32x4& zD, bf16x8& zb0, bf16x8& zb1)
{
    #pragma unroll
    for (int j = 0; j < 8; ++j) {
        u32x2 pv = { pkbf(xr[4*j+0], xr[4*j+1]), pkbf(xr[4*j+2], xr[4*j+3]) };
        *(u32x2*)(xrow + lg * 32 + 4 * j) = pv;   // ds_write_b64
    }
    zA = *(const f32x4*)(sBias +  0 + klg);
    zB = *(const f32x4*)(sBias + 16 + klg);
    zC = *(const f32x4*)(sBias + 32 + klg);
    zD = *(const f32x4*)(sBias + 48 + klg);
    #pragma unroll
    for (int ks = 0; ks < 4; ++ks) {
        bf16x8 xf = *(const bf16x8*)(xrow + ks * 32 + lg * 8);
        bf16x8 w0 = *(const bf16x8*)(sWA + ((0 * 4 + ks) * 64 + l) * 8);
        bf16x8 w1 = *(const bf16x8*)(sWA + ((1 * 4 + ks) * 64 + l) * 8);
        bf16x8 w2 = *(const bf16x8*)(sWA + ((2 * 4 + ks) * 64 + l) * 8);
        bf16x8 w3 = *(const bf16x8*)(sWA + ((3 * 4 + ks) * 64 + l) * 8);
        zA = MFMA16(w0, xf, zA);
        zB = MFMA16(w1, xf, zB);
        zC = MFMA16(w2, xf, zC);
        zD = MFMA16(w3, xf, zD);
    }
    // z -> bf16 -> same slot row (same-wave LDS ordering via lgkmcnt)
    unsigned int* zr = (unsigned int*)xrow;
    u32x2 z0 = { pkbf(zA[0], zA[1]), pkbf(zA[2], zA[3]) };
    u32x2 z1 = { pkbf(zB[0], zB[1]), pkbf(zB[2], zB[3]) };
    u32x2 z2 = { pkbf(zC[0], zC[1]), pkbf(zC[2], zC[3]) };
    u32x2 z3 = { pkbf(zD[0], zD[1]), pkbf(zD[2], zD[3]) };
    *(u32x2*)(zr +  0 + lg * 2) = z0;
    *(u32x2*)(zr +  8 + lg * 2) = z1;
    *(u32x2*)(zr + 16 + lg * 2) = z2;
    *(u32x2*)(zr + 24 + lg * 2) = z3;
    zb0 = *(const bf16x8*)(xrow + lg * 8);        // d = lg*8 + e
    zb1 = *(const bf16x8*)(xrow + 32 + lg * 8);   // d = 32 + lg*8 + e
}

// ---------------------------------------------------------------------------
// R7 monolith (proven 49 us) + two changes:
//  (i) x loads issued BEFORE prologue staging -> x HBM window hidden under
//      fragment staging + barrier (vmcnt in-order: staging completes after
//      max(x, staging), not the serial sum R7 paid).
// (ii) no atomics: per-block partial -> part[bid]; 1-block vq_loss reduces.
// ---------------------------------------------------------------------------
__global__ __launch_bounds__(1024, 4) void vq_mfma(
    const float* __restrict__ x,      // [32][128][4096]
    const float* __restrict__ w,      // [64][128]
    const float* __restrict__ bias,   // [64]
    const float* __restrict__ cb,     // [512][64]
    float* __restrict__ out,          // [32][64][4096]
    float* __restrict__ part)         // [256]
{
    __shared__ __align__(16) unsigned short sCbA[KCB * DDIM];   // 64 KB -2c A-frags
    __shared__ __align__(16) unsigned short sWA[DDIM * CIN];    // 16 KB W A-frags
    __shared__ __align__(16) float sCbn[KCB];                   // 2 KB
    __shared__ __align__(16) float sBias[DDIM];                 // 256 B
    __shared__ __align__(16) unsigned short sX[16 * 16 * XPAD]; // 68 KB wave slots
    __shared__ float sLoss[16];

    const int t   = threadIdx.x;
    const int l   = t & 63;
    const int wv  = t >> 6;
    const int p16 = l & 15;
    const int lg  = l >> 4;
    const int klg = lg * 4;

    // ===== (i) issue this wave's x loads FIRST (independent of staging) =====
    const int b   = blockIdx.x >> 3;
    const int hw0 = (blockIdx.x & 7) * 512 + wv * 32;
    const float* xp = x + ((size_t)b * CIN + (size_t)lg * 32) * HWSZ + hw0 + p16;
    float xr0[32], xr1[32];
    #pragma unroll
    for (int j = 0; j < 32; ++j) {             // paired: full 128B line per plane
        xr0[j] = xp[(size_t)j * HWSZ];
        xr1[j] = xp[(size_t)j * HWSZ + 16];
    }

    // ===== prologue: cooperative fragment staging (verified R5-R7) =====
    #pragma unroll
    for (int it = 0; it < 8; ++it) {           // cb A-frags: A[k][d] = -2*cb
        int i = t + it * 1024;
        int k = i >> 4, dg = i & 15;
        f32x4 v = *(const f32x4*)(cb + (size_t)k * DDIM + dg * 4);
        u32x2 pv = { pkbf(-2.f * v[0], -2.f * v[1]), pkbf(-2.f * v[2], -2.f * v[3]) };
        int ct = k >> 4, ks = dg >> 3, lhi = (dg >> 1) & 3, ll = (k & 15) | (lhi << 4);
        *(u32x2*)(sCbA + ((ct * 2 + ks) * 64 + ll) * 8 + (dg & 1) * 4) = pv;
    }
    #pragma unroll
    for (int it = 0; it < 2; ++it) {           // W A-frags: A[d][c]
        int i = t + it * 1024;
        int d = i >> 5, cg = i & 31;
        f32x4 v = *(const f32x4*)(w + (size_t)d * CIN + cg * 4);
        u32x2 pv = { pkbf(v[0], v[1]), pkbf(v[2], v[3]) };
        int dt = d >> 4, ks = cg >> 3, lhi = (cg >> 1) & 3, ll = (d & 15) | (lhi << 4);
        *(u32x2*)(sWA + ((dt * 4 + ks) * 64 + ll) * 8 + (cg & 1) * 4) = pv;
    }
    if (t < KCB) {                             // ||c_k||^2 (f32)
        const f32x4* row = (const f32x4*)(cb + (size_t)t * DDIM);
        float s = 0.f;
        #pragma unroll
        for (int j = 0; j < DDIM / 4; ++j) {
            f32x4 v = row[j];
            s = fmaf(v[0], v[0], s); s = fmaf(v[1], v[1], s);
            s = fmaf(v[2], v[2], s); s = fmaf(v[3], v[3], s);
        }
        sCbn[t] = s;
    }
    if (t < DDIM) sBias[t] = bias[t];
    __syncthreads();

    // ===== per-wave pipeline: 2 ADJACENT tiles (hw +0 / +16) =====
    unsigned short* xrow = sX + wv * (16 * XPAD) + p16 * XPAD;

    f32x4 zaA0, zaA1, zaA2, zaA3, zaB0, zaB1, zaB2, zaB3;
    bf16x8 zb00, zb01, zb10, zb11;
    proj_tile(xr0, xrow, sWA, sBias, lg, klg, l, zaA0, zaA1, zaA2, zaA3, zb00, zb01);
    proj_tile(xr1, xrow, sWA, sBias, lg, klg, l, zaB0, zaB1, zaB2, zaB3, zb10, zb11);

    // ---- phase B: one codebook scan, both tiles; packed-key argmin ----
    float rm00 = INFINITY, rm01 = INFINITY, rm10 = INFINITY, rm11 = INFINITY;
    #pragma unroll 4
    for (int ct = 0; ct < 32; ++ct) {
        f32x4 cinit = *(const f32x4*)(sCbn + ct * 16 + klg);   // init = ||c||^2
        bf16x8 c0 = *(const bf16x8*)(sCbA + ((ct * 2 + 0) * 64 + l) * 8);
        bf16x8 c1 = *(const bf16x8*)(sCbA + ((ct * 2 + 1) * 64 + l) * 8);
        f32x4 a0 = MFMA16(c0, zb00, cinit); a0 = MFMA16(c1, zb01, a0);
        f32x4 a1 = MFMA16(c0, zb10, cinit); a1 = MFMA16(c1, zb11, a1);
        unsigned int kb = (unsigned int)(ct * 16 + klg);
        rm00 = fminf(rm00, bcf((bcu(a0[0]) & 0xFFFFFE00u) | (kb + 0)));
        rm01 = fminf(rm01, bcf((bcu(a0[1]) & 0xFFFFFE00u) | (kb + 1)));
        rm00 = fminf(rm00, bcf((bcu(a0[2]) & 0xFFFFFE00u) | (kb + 2)));
        rm01 = fminf(rm01, bcf((bcu(a0[3]) & 0xFFFFFE00u) | (kb + 3)));
        rm10 = fminf(rm10, bcf((bcu(a1[0]) & 0xFFFFFE00u) | (kb + 0)));
        rm11 = fminf(rm11, bcf((bcu(a1[1]) & 0xFFFFFE00u) | (kb + 1)));
        rm10 = fminf(rm10, bcf((bcu(a1[2]) & 0xFFFFFE00u) | (kb + 2)));
        rm11 = fminf(rm11, bcf((bcu(a1[3]) & 0xFFFFFE00u) | (kb + 3)));
    }
    float rn0 = fminf(rm00, rm01);
    rn0 = fminf(rn0, __shfl_xor(rn0, 16, 64));
    rn0 = fminf(rn0, __shfl_xor(rn0, 32, 64));
    const int kbest0 = (int)(bcu(rn0) & 511u);
    float rn1 = fminf(rm10, rm11);
    rn1 = fminf(rn1, __shfl_xor(rn1, 16, 64));
    rn1 = fminf(rn1, __shfl_xor(rn1, 32, 64));
    const int kbest1 = (int)(bcu(rn1) & 511u);

    // ---- gather winners (exact f32), interleaved stores (R7 pattern) ----
    const float* q0r = cb + (size_t)kbest0 * DDIM;   // L2-hot
    const float* q1r = cb + (size_t)kbest1 * DDIM;
    f32x4 qa0 = *(const f32x4*)(q0r +  0 + klg), qb0 = *(const f32x4*)(q1r +  0 + klg);
    f32x4 qa1 = *(const f32x4*)(q0r + 16 + klg), qb1 = *(const f32x4*)(q1r + 16 + klg);
    f32x4 qa2 = *(const f32x4*)(q0r + 32 + klg), qb2 = *(const f32x4*)(q1r + 32 + klg);
    f32x4 qa3 = *(const f32x4*)(q0r + 48 + klg), qb3 = *(const f32x4*)(q1r + 48 + klg);
    float lsum = 0.f;
    size_t ob = ((size_t)b * DDIM + klg) * (size_t)HWSZ + hw0 + p16;
    #pragma unroll
    for (int r = 0; r < 4; ++r) {
        float e;
        e = qa0[r] - zaA0[r]; lsum = fmaf(e, e, lsum);
        e = qb0[r] - zaB0[r]; lsum = fmaf(e, e, lsum);
        e = qa1[r] - zaA1[r]; lsum = fmaf(e, e, lsum);
        e = qb1[r] - zaB1[r]; lsum = fmaf(e, e, lsum);
        e = qa2[r] - zaA2[r]; lsum = fmaf(e, e, lsum);
        e = qb2[r] - zaB2[r]; lsum = fmaf(e, e, lsum);
        e = qa3[r] - zaA3[r]; lsum = fmaf(e, e, lsum);
        e = qb3[r] - zaB3[r]; lsum = fmaf(e, e, lsum);
        out[ob + (size_t)(r +  0) * HWSZ]      = qa0[r];
        out[ob + (size_t)(r +  0) * HWSZ + 16] = qb0[r];
        out[ob + (size_t)(r + 16) * HWSZ]      = qa1[r];
        out[ob + (size_t)(r + 16) * HWSZ + 16] = qb1[r];
        out[ob + (size_t)(r + 32) * HWSZ]      = qa2[r];
        out[ob + (size_t)(r + 32) * HWSZ + 16] = qb2[r];
        out[ob + (size_t)(r + 48) * HWSZ]      = qa3[r];
        out[ob + (size_t)(r + 48) * HWSZ + 16] = qb3[r];
    }

    // ---- (ii) loss: wave reduce -> LDS -> block reduce -> part[bid] ----
    #pragma unroll
    for (int off = 32; off > 0; off >>= 1)
        lsum += __shfl_down(lsum, off, 64);
    if (l == 0) sLoss[wv] = lsum;
    __syncthreads();
    if (wv == 0) {
        float v = (l < 16) ? sLoss[l] : 0.f;
        v += __shfl_down(v, 8, 64);
        v += __shfl_down(v, 4, 64);
        v += __shfl_down(v, 2, 64);
        v += __shfl_down(v, 1, 64);
        if (l == 0) part[blockIdx.x] = v;
    }
}

// ---------------------------------------------------------------------------
// final loss reduce: 1 block x 256 thr, single writer, deterministic.
// ---------------------------------------------------------------------------
__global__ __launch_bounds__(256) void vq_loss(
    const float* __restrict__ part, float* __restrict__ loss_slot)
{
    __shared__ float sW[4];
    const int t = threadIdx.x;
    float s = part[t];
    #pragma unroll
    for (int off = 32; off > 0; off >>= 1) s += __shfl_down(s, off, 64);
    if ((t & 63) == 0) sW[t >> 6] = s;
    __syncthreads();
    if (t == 0)
        *loss_slot = (sW[0] + sW[1] + sW[2] + sW[3]) * (1.25f / (float)NOUTQ);
}

extern "C" void kernel_launch(void* const* d_in, const int* in_sizes, int n_in,
                              void* d_out, int out_size, void* d_ws, size_t ws_size,
                              hipStream_t stream) {
    const float* x    = (const float*)d_in[0];   // [32,128,64,64]
    const float* w    = (const float*)d_in[1];   // [64,128]
    const float* bias = (const float*)d_in[2];   // [64]
    const float* cb   = (const float*)d_in[3];   // [512,64]
    float* out = (float*)d_out;                  // 8388608 quantized + 1 loss
    float* loss_slot = out + NOUTQ;
    float* part = (float*)d_ws;                  // 256 f32

    vq_mfma<<<256, 1024, 0, stream>>>(x, w, bias, cb, out, part);
    vq_loss<<<1,   256,  0, stream>>>(part, loss_slot);
}